// Round 1
// baseline (140.366 us; speedup 1.0000x reference)
//
#include <hip/hip_runtime.h>

typedef float v2f __attribute__((ext_vector_type(2)));

#define NB 32
#define N0 20000
#define N1 10000
#define N2 10000
#define NT_A 157           // ceil(10000 float4 / 64)
#define T_A 14             // A-role t-chunks per (b, side, ccHalf)
#define KC_A 8
#define KC_B 16
#define NBINS 4096
#define SENT 3.0e4f        // sentinel: per-term contribution ~ -1e-10

// grid = 2048 blocks exactly (= 256 CU x 8 blocks/CU, one dispatch round).
// Every 8th block (slot&7==0) is a B-role block (256 total, ~1 per CU under
// any dispatch order); the other 1792 are A-role. All atomicAdd into
// memset-zeroed out[0..4095].
__global__ __launch_bounds__(256, 8) void hat_kernel(
    const float* __restrict__ up0, const float* __restrict__ down0,
    const float* __restrict__ ext0, const float* __restrict__ ext1,
    const float* __restrict__ centers, const float* __restrict__ radius,
    float* __restrict__ out)
{
    const int tid  = threadIdx.x;
    const int lane = tid & 63;
    const int wave = tid >> 6;
    const float r  = fabsf(radius[0]);

    __shared__ unsigned hist[NBINS];     // 16 KB (B-role)
    __shared__ float    red[4 * KC_B];   // B-role cross-wave reduction

    const int slot = blockIdx.x;

    if ((slot & 7) == 0) {
        // ================= B-role: ext points, 1-D binned =================
        const int id   = slot >> 3;      // [0, 256)
        const int cc   = id & 3;         // 4 chunks of 16 centers
        const int side = (id >> 2) & 1;  // 0 = up (use y), 1 = down (use x)
        const int b    = id >> 3;
        const int cbase = cc * KC_B;

        for (int j = tid; j < NBINS; j += 256) hist[j] = 0;
        __syncthreads();

        const float2* e0 = (const float2*)(ext0 + (size_t)b * (N1*2));
        const float2* e1 = (const float2*)(ext1 + (size_t)b * (N2*2));
        for (int i = tid; i < N1; i += 256) {
            const float2 q0 = e0[i];
            const float2 q1 = e1[i];
            const float vv0 = (side == 0) ? q0.y : q0.x;
            const float vv1 = (side == 0) ? q1.y : q1.x;
            int b0 = (int)(vv0 * (float)NBINS);
            int b1 = (int)(vv1 * (float)NBINS);
            b0 = min(max(b0, 0), NBINS - 1);
            b1 = min(max(b1, 0), NBINS - 1);
            atomicAdd(&hist[b0], 1u);
            atomicAdd(&hist[b1], 1u);
        }
        __syncthreads();

        // centers: n_k(vv) = max(|1-uc_k|, 2|vv - (1+vc_k)/2|)
        float Ak[KC_B], mk[KC_B];
        #pragma unroll
        for (int k = 0; k < KC_B; ++k) {
            const float cx = centers[2*(cbase+k)];
            const float cy = centers[2*(cbase+k)+1];
            Ak[k] = fabsf(1.0f - (cx + cy));
            mk[k] = 0.5f * (1.0f + (cx - cy));
        }

        float part[KC_B];
        #pragma unroll
        for (int k = 0; k < KC_B; ++k) part[k] = 0.f;

        #pragma unroll
        for (int jj = 0; jj < NBINS/256; ++jj) {
            const int j = jj*256 + tid;
            const float cntf = (float)hist[j];
            const float vvj  = ((float)j + 0.5f) * (1.0f/(float)NBINS);
            #pragma unroll
            for (int k = 0; k < KC_B; ++k) {
                const float s  = vvj - mk[k];
                const float tt = fmaxf(Ak[k], 2.0f*fabsf(s));
                const float d1 = 1.0f + tt;
                const float rn = r - tt;
                const float d2 = 1.0f + fabsf(rn);
                const float rc = __builtin_amdgcn_rcpf(d1 * d2);
                part[k] = fmaf(cntf * (d2 - d1), rc, part[k]);
            }
        }

        // KC=16 butterfly (R6-validated): center (lane>>2)&15 in part[0]
        {
            #pragma unroll
            for (int k = 0; k < 8; ++k) {
                const bool hi = lane & 32;
                const float send = hi ? part[k]   : part[k+8];
                const float keep = hi ? part[k+8] : part[k];
                part[k] = keep + __shfl_xor(send, 32, 64);
            }
            #pragma unroll
            for (int k = 0; k < 4; ++k) {
                const bool hi = lane & 16;
                const float send = hi ? part[k]   : part[k+4];
                const float keep = hi ? part[k+4] : part[k];
                part[k] = keep + __shfl_xor(send, 16, 64);
            }
            #pragma unroll
            for (int k = 0; k < 2; ++k) {
                const bool hi = lane & 8;
                const float send = hi ? part[k]   : part[k+2];
                const float keep = hi ? part[k+2] : part[k];
                part[k] = keep + __shfl_xor(send, 8, 64);
            }
            {
                const bool hi = lane & 4;
                const float send = hi ? part[0] : part[1];
                const float keep = hi ? part[1] : part[0];
                part[0] = keep + __shfl_xor(send, 4, 64);
            }
            part[0] += __shfl_xor(part[0], 2, 64);
            part[0] += __shfl_xor(part[0], 1, 64);
        }
        if ((lane & 3) == 0) red[wave * KC_B + (lane >> 2)] = part[0];
        __syncthreads();
        if (tid < KC_B) {
            const float s = red[tid] + red[KC_B + tid] + red[2*KC_B + tid] + red[3*KC_B + tid];
            atomicAdd(&out[b*128 + side*64 + cbase + tid], s);
        }
        return;
    }

    // ================= A-role: beta_0 points, exact =================
    // aid in [0, 1792) = 32 b x 2 side x 14 tchunk x 2 half
    const int aid    = slot - (slot >> 3) - 1;
    const int half   = aid & 1;                 // which 32-center half
    const int rest0  = aid >> 1;                // [0, 896)
    const int tchunk = rest0 % T_A;             // [0, 14)
    const int rest1  = rest0 / T_A;             // [0, 64)
    const int side   = rest1 & 1;
    const int b      = rest1 >> 1;
    const int cbase  = (half * 4 + wave) * KC_A;   // per-wave center group

    v2f nuc[KC_A], nvc[KC_A];
    #pragma unroll
    for (int k = 0; k < KC_A; ++k) {
        const float cx = centers[2*(cbase+k)];
        const float cy = centers[2*(cbase+k)+1];
        nuc[k] = (v2f){-(cx + cy), -(cx + cy)};
        nvc[k] = (v2f){-(cx - cy), -(cx - cy)};
    }

    const float4* base0 = (const float4*)((side == 0 ? up0 : down0) + (size_t)b * (N0*2));

    v2f acc[KC_A];
    #pragma unroll
    for (int k = 0; k < KC_A; ++k) acc[k] = (v2f){0.f, 0.f};
    const v2f one2 = (v2f){1.f, 1.f};

    // All 4 waves of this block walk the SAME chunk stream (L1 reuse),
    // each evaluating its own 8-center group.
    for (int t = tchunk; t < NT_A; t += T_A) {
        const int i = t*64 + lane;      // float4 index = two points
        v2f u_, v_;
        if (i < N0/2) {
            const float4 q = base0[i];
            u_ = (v2f){q.x + q.y, q.z + q.w};
            v_ = (v2f){q.x - q.y, q.z - q.w};
        } else {
            u_ = (v2f){SENT, SENT};
            v_ = (v2f){0.f, 0.f};
        }

        #pragma unroll
        for (int k = 0; k < KC_A; ++k) {
            const v2f du = u_ + nuc[k];
            const v2f dv = v_ + nvc[k];
            const float tt0 = fmaxf(fabsf(du.x), fabsf(dv.x));
            const float tt1 = fmaxf(fabsf(du.y), fabsf(dv.y));
            const v2f tt = (v2f){tt0, tt1};
            const v2f d1 = tt + one2;
            const float rn0 = r - tt0;
            const float rn1 = r - tt1;
            const v2f d2 = (v2f){1.f + fabsf(rn0), 1.f + fabsf(rn1)};
            const v2f dd  = d1 * d2;
            const v2f num = d2 - d1;
            const v2f rc  = (v2f){__builtin_amdgcn_rcpf(dd.x),
                                  __builtin_amdgcn_rcpf(dd.y)};
            acc[k] = __builtin_elementwise_fma(num, rc, acc[k]);
        }
    }

    float a1[KC_A];
    #pragma unroll
    for (int k = 0; k < KC_A; ++k) a1[k] = acc[k].x + acc[k].y;

    // KC=8 butterfly (R7/R8-validated): center (lane>>3)&7 at (lane&7)==0
    {
        #pragma unroll
        for (int k = 0; k < 4; ++k) {
            const bool hi = lane & 32;
            const float send = hi ? a1[k]   : a1[k+4];
            const float keep = hi ? a1[k+4] : a1[k];
            a1[k] = keep + __shfl_xor(send, 32, 64);
        }
        #pragma unroll
        for (int k = 0; k < 2; ++k) {
            const bool hi = lane & 16;
            const float send = hi ? a1[k]   : a1[k+2];
            const float keep = hi ? a1[k+2] : a1[k];
            a1[k] = keep + __shfl_xor(send, 16, 64);
        }
        {
            const bool hi = lane & 8;
            const float send = hi ? a1[0] : a1[1];
            const float keep = hi ? a1[1] : a1[0];
            a1[0] = keep + __shfl_xor(send, 8, 64);
        }
        a1[0] += __shfl_xor(a1[0], 4, 64);
        a1[0] += __shfl_xor(a1[0], 2, 64);
        a1[0] += __shfl_xor(a1[0], 1, 64);
    }
    // Each wave owns its own 8 centers: no LDS, no __syncthreads needed.
    if ((lane & 7) == 0) {
        atomicAdd(&out[b*128 + side*64 + cbase + (lane >> 3)], a1[0]);
    }
}

__global__ __launch_bounds__(256) void tpl_kernel(float* __restrict__ out)
{
    __shared__ float red[256];
    float s = 0.f;
    for (int i = threadIdx.x; i < NB*64; i += 256) {
        const int b = i >> 6, k = i & 63;
        const float d = out[b*128 + k] - out[b*128 + 64 + k];
        s = fmaf(d, d, s);
    }
    red[threadIdx.x] = s;
    __syncthreads();
    for (int w = 128; w > 0; w >>= 1) {
        if (threadIdx.x < w) red[threadIdx.x] += red[threadIdx.x + w];
        __syncthreads();
    }
    if (threadIdx.x == 0) out[NB*128] = -red[0];
}

extern "C" void kernel_launch(void* const* d_in, const int* in_sizes, int n_in,
                              void* d_out, int out_size, void* d_ws, size_t ws_size,
                              hipStream_t stream) {
    const float* up0     = (const float*)d_in[0];
    const float* down0   = (const float*)d_in[1];
    const float* ext0    = (const float*)d_in[2];
    const float* ext1    = (const float*)d_in[3];
    const float* centers = (const float*)d_in[4];
    const float* radius  = (const float*)d_in[5];
    float* out = (float*)d_out;

    // accumulator region must start at zero (harness poisons d_out with 0xAA)
    hipMemsetAsync(out, 0, NB * 128 * sizeof(float), stream);

    hat_kernel<<<dim3(2048), dim3(256), 0, stream>>>(
        up0, down0, ext0, ext1, centers, radius, out);
    tpl_kernel<<<1, 256, 0, stream>>>(out);
}

// Round 2
// 105.677 us; speedup vs baseline: 1.3283x; 1.3283x over previous
//
#include <hip/hip_runtime.h>

typedef float v2f __attribute__((ext_vector_type(2)));

#define NB 32
#define N0 20000
#define N1 10000
#define N2 10000
#define NT_A 157           // ceil(10000 float4 / 64)
#define T_A 14             // A-role t-chunks per (b, side, ccHalf)
#define KC_A 8
#define KC_B 16
#define NBINS 4096
#define SENT 3.0e4f        // sentinel: per-term contribution ~ -1e-10

// grid = 2048 blocks exactly (= 256 CU x 8 blocks/CU, one dispatch round).
// Blocks 0..255 are B-role (ext/binned): contiguous blockIdx round-robins
// across the 8 XCDs -> 32 B-blocks per XCD = 1 per CU, and they dispatch
// first (head start for the heavy role). NOTE: do NOT select B-role by
// (slot&7)==0 -- blockIdx%8 is the XCD index, so that stacks all B-blocks
// on XCD 0 (R1 regression, 72us vs 57us).
// Blocks 256..2047 are A-role (exact beta_0). All atomicAdd into
// memset-zeroed out[0..4095].
__global__ __launch_bounds__(256, 8) void hat_kernel(
    const float* __restrict__ up0, const float* __restrict__ down0,
    const float* __restrict__ ext0, const float* __restrict__ ext1,
    const float* __restrict__ centers, const float* __restrict__ radius,
    float* __restrict__ out)
{
    const int tid  = threadIdx.x;
    const int lane = tid & 63;
    const int wave = tid >> 6;
    const float r  = fabsf(radius[0]);

    __shared__ unsigned hist[NBINS];     // 16 KB (B-role)
    __shared__ float    red[4 * KC_B];   // B-role cross-wave reduction

    const int slot = blockIdx.x;

    if (slot < 256) {
        // ================= B-role: ext points, 1-D binned =================
        const int id   = slot;           // [0, 256)
        const int cc   = id & 3;         // 4 chunks of 16 centers
        const int side = (id >> 2) & 1;  // 0 = up (use y), 1 = down (use x)
        const int b    = id >> 3;
        const int cbase = cc * KC_B;

        for (int j = tid; j < NBINS; j += 256) hist[j] = 0;
        __syncthreads();

        const float2* e0 = (const float2*)(ext0 + (size_t)b * (N1*2));
        const float2* e1 = (const float2*)(ext1 + (size_t)b * (N2*2));
        for (int i = tid; i < N1; i += 256) {
            const float2 q0 = e0[i];
            const float2 q1 = e1[i];
            const float vv0 = (side == 0) ? q0.y : q0.x;
            const float vv1 = (side == 0) ? q1.y : q1.x;
            int b0 = (int)(vv0 * (float)NBINS);
            int b1 = (int)(vv1 * (float)NBINS);
            b0 = min(max(b0, 0), NBINS - 1);
            b1 = min(max(b1, 0), NBINS - 1);
            atomicAdd(&hist[b0], 1u);
            atomicAdd(&hist[b1], 1u);
        }
        __syncthreads();

        // centers: n_k(vv) = max(|1-uc_k|, 2|vv - (1+vc_k)/2|)
        float Ak[KC_B], mk[KC_B];
        #pragma unroll
        for (int k = 0; k < KC_B; ++k) {
            const float cx = centers[2*(cbase+k)];
            const float cy = centers[2*(cbase+k)+1];
            Ak[k] = fabsf(1.0f - (cx + cy));
            mk[k] = 0.5f * (1.0f + (cx - cy));
        }

        float part[KC_B];
        #pragma unroll
        for (int k = 0; k < KC_B; ++k) part[k] = 0.f;

        #pragma unroll
        for (int jj = 0; jj < NBINS/256; ++jj) {
            const int j = jj*256 + tid;
            const float cntf = (float)hist[j];
            const float vvj  = ((float)j + 0.5f) * (1.0f/(float)NBINS);
            #pragma unroll
            for (int k = 0; k < KC_B; ++k) {
                const float s  = vvj - mk[k];
                const float tt = fmaxf(Ak[k], 2.0f*fabsf(s));
                const float d1 = 1.0f + tt;
                const float rn = r - tt;
                const float d2 = 1.0f + fabsf(rn);
                const float rc = __builtin_amdgcn_rcpf(d1 * d2);
                part[k] = fmaf(cntf * (d2 - d1), rc, part[k]);
            }
        }

        // KC=16 butterfly (R6-validated): center (lane>>2)&15 in part[0]
        {
            #pragma unroll
            for (int k = 0; k < 8; ++k) {
                const bool hi = lane & 32;
                const float send = hi ? part[k]   : part[k+8];
                const float keep = hi ? part[k+8] : part[k];
                part[k] = keep + __shfl_xor(send, 32, 64);
            }
            #pragma unroll
            for (int k = 0; k < 4; ++k) {
                const bool hi = lane & 16;
                const float send = hi ? part[k]   : part[k+4];
                const float keep = hi ? part[k+4] : part[k];
                part[k] = keep + __shfl_xor(send, 16, 64);
            }
            #pragma unroll
            for (int k = 0; k < 2; ++k) {
                const bool hi = lane & 8;
                const float send = hi ? part[k]   : part[k+2];
                const float keep = hi ? part[k+2] : part[k];
                part[k] = keep + __shfl_xor(send, 8, 64);
            }
            {
                const bool hi = lane & 4;
                const float send = hi ? part[0] : part[1];
                const float keep = hi ? part[1] : part[0];
                part[0] = keep + __shfl_xor(send, 4, 64);
            }
            part[0] += __shfl_xor(part[0], 2, 64);
            part[0] += __shfl_xor(part[0], 1, 64);
        }
        if ((lane & 3) == 0) red[wave * KC_B + (lane >> 2)] = part[0];
        __syncthreads();
        if (tid < KC_B) {
            const float s = red[tid] + red[KC_B + tid] + red[2*KC_B + tid] + red[3*KC_B + tid];
            atomicAdd(&out[b*128 + side*64 + cbase + tid], s);
        }
        return;
    }

    // ================= A-role: beta_0 points, exact =================
    // aid in [0, 1792) = 32 b x 2 side x 14 tchunk x 2 half
    const int aid    = slot - 256;
    const int half   = aid & 1;                 // which 32-center half
    const int rest0  = aid >> 1;                // [0, 896)
    const int tchunk = rest0 % T_A;             // [0, 14)
    const int rest1  = rest0 / T_A;             // [0, 64)
    const int side   = rest1 & 1;
    const int b      = rest1 >> 1;
    const int cbase  = (half * 4 + wave) * KC_A;   // per-wave center group

    v2f nuc[KC_A], nvc[KC_A];
    #pragma unroll
    for (int k = 0; k < KC_A; ++k) {
        const float cx = centers[2*(cbase+k)];
        const float cy = centers[2*(cbase+k)+1];
        nuc[k] = (v2f){-(cx + cy), -(cx + cy)};
        nvc[k] = (v2f){-(cx - cy), -(cx - cy)};
    }

    const float4* base0 = (const float4*)((side == 0 ? up0 : down0) + (size_t)b * (N0*2));

    v2f acc[KC_A];
    #pragma unroll
    for (int k = 0; k < KC_A; ++k) acc[k] = (v2f){0.f, 0.f};
    const v2f one2 = (v2f){1.f, 1.f};

    // All 4 waves of this block walk the SAME chunk stream (L1 reuse),
    // each evaluating its own 8-center group.
    for (int t = tchunk; t < NT_A; t += T_A) {
        const int i = t*64 + lane;      // float4 index = two points
        v2f u_, v_;
        if (i < N0/2) {
            const float4 q = base0[i];
            u_ = (v2f){q.x + q.y, q.z + q.w};
            v_ = (v2f){q.x - q.y, q.z - q.w};
        } else {
            u_ = (v2f){SENT, SENT};
            v_ = (v2f){0.f, 0.f};
        }

        #pragma unroll
        for (int k = 0; k < KC_A; ++k) {
            const v2f du = u_ + nuc[k];
            const v2f dv = v_ + nvc[k];
            const float tt0 = fmaxf(fabsf(du.x), fabsf(dv.x));
            const float tt1 = fmaxf(fabsf(du.y), fabsf(dv.y));
            const v2f tt = (v2f){tt0, tt1};
            const v2f d1 = tt + one2;
            const float rn0 = r - tt0;
            const float rn1 = r - tt1;
            const v2f d2 = (v2f){1.f + fabsf(rn0), 1.f + fabsf(rn1)};
            const v2f dd  = d1 * d2;
            const v2f num = d2 - d1;
            const v2f rc  = (v2f){__builtin_amdgcn_rcpf(dd.x),
                                  __builtin_amdgcn_rcpf(dd.y)};
            acc[k] = __builtin_elementwise_fma(num, rc, acc[k]);
        }
    }

    float a1[KC_A];
    #pragma unroll
    for (int k = 0; k < KC_A; ++k) a1[k] = acc[k].x + acc[k].y;

    // KC=8 butterfly (R7/R8-validated): center (lane>>3)&7 at (lane&7)==0
    {
        #pragma unroll
        for (int k = 0; k < 4; ++k) {
            const bool hi = lane & 32;
            const float send = hi ? a1[k]   : a1[k+4];
            const float keep = hi ? a1[k+4] : a1[k];
            a1[k] = keep + __shfl_xor(send, 32, 64);
        }
        #pragma unroll
        for (int k = 0; k < 2; ++k) {
            const bool hi = lane & 16;
            const float send = hi ? a1[k]   : a1[k+2];
            const float keep = hi ? a1[k+2] : a1[k];
            a1[k] = keep + __shfl_xor(send, 16, 64);
        }
        {
            const bool hi = lane & 8;
            const float send = hi ? a1[0] : a1[1];
            const float keep = hi ? a1[1] : a1[0];
            a1[0] = keep + __shfl_xor(send, 8, 64);
        }
        a1[0] += __shfl_xor(a1[0], 4, 64);
        a1[0] += __shfl_xor(a1[0], 2, 64);
        a1[0] += __shfl_xor(a1[0], 1, 64);
    }
    // Each wave owns its own 8 centers: no LDS, no __syncthreads needed.
    if ((lane & 7) == 0) {
        atomicAdd(&out[b*128 + side*64 + cbase + (lane >> 3)], a1[0]);
    }
}

__global__ __launch_bounds__(256) void tpl_kernel(float* __restrict__ out)
{
    __shared__ float red[256];
    float s = 0.f;
    for (int i = threadIdx.x; i < NB*64; i += 256) {
        const int b = i >> 6, k = i & 63;
        const float d = out[b*128 + k] - out[b*128 + 64 + k];
        s = fmaf(d, d, s);
    }
    red[threadIdx.x] = s;
    __syncthreads();
    for (int w = 128; w > 0; w >>= 1) {
        if (threadIdx.x < w) red[threadIdx.x] += red[threadIdx.x + w];
        __syncthreads();
    }
    if (threadIdx.x == 0) out[NB*128] = -red[0];
}

extern "C" void kernel_launch(void* const* d_in, const int* in_sizes, int n_in,
                              void* d_out, int out_size, void* d_ws, size_t ws_size,
                              hipStream_t stream) {
    const float* up0     = (const float*)d_in[0];
    const float* down0   = (const float*)d_in[1];
    const float* ext0    = (const float*)d_in[2];
    const float* ext1    = (const float*)d_in[3];
    const float* centers = (const float*)d_in[4];
    const float* radius  = (const float*)d_in[5];
    float* out = (float*)d_out;

    // accumulator region must start at zero (harness poisons d_out with 0xAA)
    hipMemsetAsync(out, 0, NB * 128 * sizeof(float), stream);

    hat_kernel<<<dim3(2048), dim3(256), 0, stream>>>(
        up0, down0, ext0, ext1, centers, radius, out);
    tpl_kernel<<<1, 256, 0, stream>>>(out);
}